// Round 1
// baseline (245.269 us; speedup 1.0000x reference)
//
#include <hip/hip_runtime.h>
#include <hip/hip_bf16.h>

#define TEMP_F   0.05f
#define B_       512
#define D_       256
#define M_       131072
#define C_       2000
#define CAP      256   // max members per cluster (Poisson lambda=65.5; P(>256) ~ 0)

typedef __attribute__((ext_vector_type(8))) short bf16x8;
typedef __attribute__((ext_vector_type(4))) float f32x4;

__device__ __forceinline__ unsigned short f2bf(float x) {
    __hip_bfloat16 h = __float2bfloat16(x);
    return *reinterpret_cast<unsigned short*>(&h);
}

__device__ __forceinline__ float block_reduce_sum256(float v, float* smem) {
    // 256 threads = 4 waves of 64
    #pragma unroll
    for (int off = 32; off >= 1; off >>= 1) v += __shfl_xor(v, off, 64);
    int wave = threadIdx.x >> 6;
    if ((threadIdx.x & 63) == 0) smem[wave] = v;
    __syncthreads();
    return smem[0] + smem[1] + smem[2] + smem[3];
}

// Kernel 1: L2-normalize results rows -> bf16 inputs; zero cursor + out.
__global__ __launch_bounds__(256) void prep_kernel(
        const float* __restrict__ results, unsigned short* __restrict__ inp,
        int* __restrict__ cursor, float* __restrict__ out) {
    __shared__ float smem[4];
    int b = blockIdx.x;
    if (b < B_) {
        float v = results[b * D_ + threadIdx.x];
        float s = block_reduce_sum256(v * v, smem);
        float inv = 1.0f / fmaxf(sqrtf(s), 1e-12f);
        inp[b * D_ + threadIdx.x] = f2bf(v * inv);
    } else {
        int i = (b - B_) * 256 + threadIdx.x;
        if (i < C_) cursor[i] = 0;
        if (i == 0) out[0] = 0.0f;
    }
}

// Kernel 2: build per-cluster member lists. cursor[c] ends as count[c].
__global__ __launch_bounds__(256) void scatter_kernel(
        const int* __restrict__ labels, int* __restrict__ cursor,
        int* __restrict__ member) {
    int m = blockIdx.x * 256 + threadIdx.x;
    int c = labels[m];
    int pos = atomicAdd(&cursor[c], 1);
    if (pos < CAP) member[c * CAP + pos] = m;
}

// Kernel 3: gather-reduce features into scaled bf16 centroids.
// cs[c][d] = (sum_{m in c} features[m][d]) / (TEMP * max(count,1))
__global__ __launch_bounds__(256) void centroid_kernel(
        const float* __restrict__ features, const int* __restrict__ cursor,
        const int* __restrict__ member, unsigned short* __restrict__ cs) {
    __shared__ int mlist[CAP];
    int c = blockIdx.x, t = threadIdx.x;
    int n = cursor[c];
    int nn = min(n, CAP);
    if (t < nn) mlist[t] = member[c * CAP + t];
    __syncthreads();
    float a0 = 0.f, a1 = 0.f, a2 = 0.f, a3 = 0.f;
    int i = 0;
    for (; i + 4 <= nn; i += 4) {
        a0 += features[(size_t)mlist[i + 0] * D_ + t];
        a1 += features[(size_t)mlist[i + 1] * D_ + t];
        a2 += features[(size_t)mlist[i + 2] * D_ + t];
        a3 += features[(size_t)mlist[i + 3] * D_ + t];
    }
    for (; i < nn; ++i) a0 += features[(size_t)mlist[i] * D_ + t];
    float acc = (a0 + a1) + (a2 + a3);
    float scale = 1.0f / (TEMP_F * (float)max(n, 1));
    cs[c * D_ + t] = f2bf(acc * scale);
}

// Kernel 4: vec[b][c] = inputs[b] . cs[c]  (bf16 MFMA, both operands row-major-K)
__global__ __launch_bounds__(256) void gemm_kernel(
        const unsigned short* __restrict__ inp, const unsigned short* __restrict__ cs,
        float* __restrict__ vec) {
    int wave = threadIdx.x >> 6;
    int lane = threadIdx.x & 63;
    int tile = blockIdx.x * 4 + wave;          // 0..3999
    int tb = tile / 125;                       // 0..31   (B tiles)
    int tc = tile - tb * 125;                  // 0..124  (C tiles)
    int row = lane & 15;
    int kg  = lane >> 4;                       // 0..3
    const unsigned short* ap = inp + (size_t)(tb * 16 + row) * D_ + kg * 8;
    const unsigned short* bp = cs  + (size_t)(tc * 16 + row) * D_ + kg * 8;
    f32x4 acc = {0.f, 0.f, 0.f, 0.f};
    #pragma unroll
    for (int k0 = 0; k0 < D_; k0 += 32) {
        bf16x8 a = *reinterpret_cast<const bf16x8*>(ap + k0);
        bf16x8 b = *reinterpret_cast<const bf16x8*>(bp + k0);
        acc = __builtin_amdgcn_mfma_f32_16x16x32_bf16(a, b, acc, 0, 0, 0);
    }
    // C/D layout: col = lane&15, row = (lane>>4)*4 + r  [measured m89]
    int ccol  = tc * 16 + (lane & 15);
    int brow0 = tb * 16 + kg * 4;
    #pragma unroll
    for (int r = 0; r < 4; ++r)
        vec[(size_t)(brow0 + r) * C_ + ccol] = acc[r];
}

// Kernel 5: masked softmax denom + NLL pick, exact reference eps semantics.
__global__ __launch_bounds__(256) void loss_kernel(
        const float* __restrict__ vec, const int* __restrict__ cursor,
        const int* __restrict__ labels, const int* __restrict__ indexes,
        float* __restrict__ out) {
    __shared__ float smem[4];
    int b = blockIdx.x, t = threadIdx.x;
    float s = 0.f;
    for (int c = t; c < C_; c += 256) {
        float v = vec[(size_t)b * C_ + c];
        s += (cursor[c] > 0) ? expf(v) : 0.f;
    }
    float S = block_reduce_sum256(s, smem);
    if (t == 0) {
        int tgt = labels[indexes[b]];
        float pt = expf(vec[(size_t)b * C_ + tgt]) / (S + 1e-6f);
        atomicAdd(out, -logf(pt + 1e-6f) * (1.0f / (float)B_));
    }
}

extern "C" void kernel_launch(void* const* d_in, const int* in_sizes, int n_in,
                              void* d_out, int out_size, void* d_ws, size_t ws_size,
                              hipStream_t stream) {
    const float* results  = (const float*)d_in[0];   // [B, D] f32
    const int*   indexes  = (const int*)d_in[1];     // [B] int
    const float* features = (const float*)d_in[2];   // [M, D] f32
    const int*   labels   = (const int*)d_in[3];     // [M] int
    float* out = (float*)d_out;                      // scalar

    char* w = (char*)d_ws;
    // workspace layout (total ~7.5 MB)
    unsigned short* inp  = (unsigned short*)(w);                    // 512*256*2   = 262144
    int*            curs = (int*)(w + 262144);                      // 2000*4      -> 8192
    int*            memb = (int*)(w + 262144 + 8192);               // 2000*256*4  -> 2097152
    unsigned short* cs   = (unsigned short*)(w + 262144 + 8192 + 2097152);          // 2000*256*2 -> 1048576
    float*          vec  = (float*)(w + 262144 + 8192 + 2097152 + 1048576);         // 512*2000*4 = 4096000

    prep_kernel<<<B_ + (C_ + 255) / 256, 256, 0, stream>>>(results, inp, curs, out);
    scatter_kernel<<<M_ / 256, 256, 0, stream>>>(labels, curs, memb);
    centroid_kernel<<<C_, 256, 0, stream>>>(features, curs, memb, cs);
    gemm_kernel<<<1000, 256, 0, stream>>>(inp, cs, vec);
    loss_kernel<<<B_, 256, 0, stream>>>(vec, curs, labels, indexes, out);
}